// Round 7
// baseline (420.621 us; speedup 1.0000x reference)
//
#include <hip/hip_runtime.h>

typedef float  f32x4 __attribute__((ext_vector_type(4)));
typedef short  s16x8 __attribute__((ext_vector_type(8)));
typedef unsigned short u16x4 __attribute__((ext_vector_type(4)));

#define AS1 __attribute__((address_space(1)))
#define AS3 __attribute__((address_space(3)))

__device__ __forceinline__ unsigned short f2bf(float x){
    union { float f; unsigned int u; } v; v.f = x;
    unsigned int r = v.u + 0x7FFFu + ((v.u >> 16) & 1u);   // RNE
    return (unsigned short)(r >> 16);
}

__device__ __forceinline__ void gload16(const unsigned short* g, const char* l){
    __builtin_amdgcn_global_load_lds((const AS1 void*)g, (AS3 void*)l, 16, 0, 0);
}

__device__ __forceinline__ void mfma16(f32x4& c, s16x8 a, s16x8 b){
    asm volatile("v_mfma_f32_16x16x32_bf16 %0, %1, %2, %0" : "+v"(c) : "v"(a), "v"(b));
}

#define GBAR() do{ asm volatile("" ::: "memory"); __builtin_amdgcn_s_barrier(); \
                   asm volatile("" ::: "memory"); }while(0)
#define VMW(N)  asm volatile("s_waitcnt vmcnt(" #N ")" ::: "memory")
#define LGKM0() asm volatile("s_waitcnt lgkmcnt(0)" ::: "memory")

// ---------------------------------------------------------------------------
// Row l2-normalize [rows][1024] f32 -> bf16. One 256-thread block per row.
// ---------------------------------------------------------------------------
__global__ __launch_bounds__(256) void norm_rows_bf16(const float* __restrict__ in,
                                                      unsigned short* __restrict__ out){
    const int row = blockIdx.x;
    const int t   = threadIdx.x;
    f32x4 x = ((const f32x4*)(in + (size_t)row * 1024))[t];
    float ss = x[0]*x[0] + x[1]*x[1] + x[2]*x[2] + x[3]*x[3];
    #pragma unroll
    for (int o = 32; o > 0; o >>= 1) ss += __shfl_xor(ss, o);
    __shared__ float red[4];
    if ((t & 63) == 0) red[t >> 6] = ss;
    __syncthreads();
    float tot = red[0] + red[1] + red[2] + red[3];
    float inv = 1.0f / fmaxf(sqrtf(tot), 1e-12f);
    u16x4 o;
    #pragma unroll
    for (int j = 0; j < 4; ++j) o[j] = f2bf(x[j] * inv);
    ((u16x4*)(out + (size_t)row * 1024))[t] = o;
}

// ---------------------------------------------------------------------------
// Final in-place row l2-normalize of d_out [N][1024] f32.
// ---------------------------------------------------------------------------
__global__ __launch_bounds__(256) void norm_rows_f32(float* __restrict__ buf){
    const int row = blockIdx.x;
    const int t   = threadIdx.x;
    f32x4* p = (f32x4*)(buf + (size_t)row * 1024);
    f32x4 x = p[t];
    float ss = x[0]*x[0] + x[1]*x[1] + x[2]*x[2] + x[3]*x[3];
    #pragma unroll
    for (int o = 32; o > 0; o >>= 1) ss += __shfl_xor(ss, o);
    __shared__ float red[4];
    if ((t & 63) == 0) red[t >> 6] = ss;
    __syncthreads();
    float tot = red[0] + red[1] + red[2] + red[3];
    float inv = 1.0f / fmaxf(sqrtf(tot), 1e-12f);
    p[t] = x * inv;
}

// ---------------------------------------------------------------------------
// offset [C=2048][D=1024] f32 -> offt [D][C] bf16 (LDS-tiled transpose),
// fused sum(offset^2) -> atomicAdd(reg_out). Tile: 64(c) x 64(d).
// ---------------------------------------------------------------------------
__global__ __launch_bounds__(256) void transpose_off(const float* __restrict__ off,
                                                     unsigned short* __restrict__ offt,
                                                     float* __restrict__ reg_out){
    __shared__ unsigned short t_lds[64][68];   // [d][c], padded row
    const int t  = threadIdx.x;
    const int c0 = blockIdx.x * 64;
    const int d0 = blockIdx.y * 64;
    float ss = 0.f;
    #pragma unroll
    for (int p = 0; p < 4; ++p){
        int c  = p * 16 + (t >> 4);
        int dq = t & 15;
        f32x4 v = *(const f32x4*)(off + (size_t)(c0 + c) * 1024 + d0 + dq * 4);
        ss += v[0]*v[0] + v[1]*v[1] + v[2]*v[2] + v[3]*v[3];
        #pragma unroll
        for (int j = 0; j < 4; ++j) t_lds[dq * 4 + j][c] = f2bf(v[j]);
    }
    __syncthreads();
    #pragma unroll
    for (int p = 0; p < 4; ++p){
        int d  = p * 16 + (t >> 4);
        int cq = t & 15;
        u16x4 o = *(const u16x4*)&t_lds[d][cq * 4];
        *(u16x4*)(offt + (size_t)(d0 + d) * 2048 + c0 + cq * 4) = o;
    }
    #pragma unroll
    for (int o = 32; o > 0; o >>= 1) ss += __shfl_xor(ss, o);
    __shared__ float red[4];
    if ((t & 63) == 0) red[t >> 6] = ss;
    __syncthreads();
    if (t == 0) atomicAdd(reg_out, red[0] + red[1] + red[2] + red[3]);
}

// ---------------------------------------------------------------------------
// GEMM: acc[m][n] = sum_k A[m][k] * B[n][k]   (both bf16, K-contiguous rows)
// 256x256 tile, BK=64, 1024 threads (16 waves, 4Mx4N; wave tile 64x64,
// acc[4][4] = 64 VGPR -> <=128 VGPR cap -> 4 waves/SIMD resident).
// 16x16x32 bf16 MFMA. Double-buffered 128 KiB LDS; buffer = 2 K-halves, each
// [A 16KB | B 16KB] (256 rows x 32 k, 64B rows, XOR granule swizzle
// g ^= (row>>1)&3 via pre-swizzled global source + swizzled ds_read; 0
// conflicts measured). 2 phases / K-tile, r6-proven ordering:
//   P(p): 8 ds_read -> vmcnt(0) [drains half staged ONE phase (~1200cyc)
//   earlier - counted-in-effect, not same-phase drain] -> barrier ->
//   stage next K-half(t+1) (2 gload_lds, in MFMA shadow) -> lgkmcnt(0)
//   [completes reads before next barrier: overwrite-safety proof] ->
//   setprio(1) + 16 MFMA + setprio(0)
// EPI==1: Wout[m][n] = bf16(exp(10*acc - 10))        (ld = ldw)
// EPI==2: Fout[m][n] = Cadd[m][n] + acc              (ld = ldo)
// ---------------------------------------------------------------------------
template<int EPI>
__global__ __launch_bounds__(1024, 4)
void gemm256(const unsigned short* __restrict__ A, int lda,
             const unsigned short* __restrict__ B, int ldb,
             int K,
             unsigned short* __restrict__ Wout, int ldw,
             const float* __restrict__ Cadd, float* __restrict__ Fout, int ldo)
{
    extern __shared__ char smem[];             // 2 x 64 KiB
    const int tid  = threadIdx.x;

    // ---- XCD-aware bijective remap (8 XCDs; L2 locality on A panels) ----
    int bx = blockIdx.x, by = blockIdx.y;
    {
        const int gx = gridDim.x, gy = gridDim.y;
        const int nwg = gx * gy;
        if ((nwg & 7) == 0){
            const int lid = bx + gx * by;
            const int q   = nwg >> 3;
            const int n   = (lid & 7) * q + (lid >> 3);
            const int sh  = 31 - __clz(gy);    // gy is a power of two here
            bx = n >> sh;
            by = n & (gy - 1);
        }
    }
    const int m0   = bx * 256;
    const int n0   = by * 256;
    const int wid  = tid >> 6, lane = tid & 63;
    const int wr   = wid >> 2, wc = wid & 3;   // 4 x 4 waves, wave tile 64x64
    const int kg   = lane >> 4, r16 = lane & 15;

    // ---- staging: per 16KB quarter (A-half or B-half), 1024 threads x 16B
    // = one gload per thread. phys granule (tid&3) at row tid>>2 holds
    // logical granule (tid&3)^((row>>1)&3) -> pre-swizzled global source.
    const int srow = tid >> 2;
    const int sg   = (tid & 3) ^ ((tid >> 3) & 3);
    const unsigned short* sA = A + (size_t)(m0 + srow) * lda + sg * 8;
    const unsigned short* sB = B + (size_t)(n0 + srow) * ldb + sg * 8;
    const int lp = tid * 16;

    // buffer layout: half h at +h*32768: [A 16KB | B 16KB]
    auto stage = [&](char* wb, int half, int ke){
        gload16(sA + ke, wb + half * 32768 + lp);
        gload16(sB + ke, wb + half * 32768 + 16384 + lp);
    };

    // ---- ds_read fragment offsets within a K-half (swizzled). Wave reads
    // 16 rows x all 4 granules = contiguous 1024B => 0 conflicts.
    int aoff[4], boff[4];
    #pragma unroll
    for (int m = 0; m < 4; ++m){
        int row = wr * 64 + m * 16 + r16;
        aoff[m] = row * 64 + ((kg ^ ((row >> 1) & 3)) << 4);
    }
    #pragma unroll
    for (int n = 0; n < 4; ++n){
        int row = wc * 64 + n * 16 + r16;
        boff[n] = 16384 + row * 64 + ((kg ^ ((row >> 1) & 3)) << 4);
    }

    f32x4 acc[4][4] = {};
    const int nsteps = K >> 6;                 // BK = 64

    // ---- prologue: stage tile 0 (half0, half1); wait half0 ----
    stage(smem, 0, 0);
    stage(smem, 1, 32);
    VMW(2);
    GBAR();

#define RD(av, bv, hb) { _Pragma("unroll") for (int m = 0; m < 4; ++m) \
    av[m] = *(const s16x8*)((hb) + aoff[m]); \
    _Pragma("unroll") for (int n = 0; n < 4; ++n) \
    bv[n] = *(const s16x8*)((hb) + boff[n]); }
#define MFMA16X(av, bv) { __builtin_amdgcn_s_setprio(1); \
    _Pragma("unroll") for (int m = 0; m < 4; ++m) \
    _Pragma("unroll") for (int n = 0; n < 4; ++n) \
        mfma16(acc[m][n], av[m], bv[n]); \
    __builtin_amdgcn_s_setprio(0); }

    s16x8 a[4], b[4];

    #pragma unroll 1
    for (int t = 0; t < nsteps - 1; ++t){
        const char* rb = smem + (t & 1) * 65536;
        char*       wb = smem + ((t + 1) & 1) * 65536;
        const int   ke = (t + 1) * 64;
        // P0: reads half0(t); drain half1(t) (staged 1 phase ago);
        //     stage half0(t+1) in MFMA shadow
        RD(a, b, rb);
        VMW(0);
        GBAR();
        stage(wb, 0, ke);
        LGKM0();
        MFMA16X(a, b);
        // P1: reads half1(t); drain half0(t+1); stage half1(t+1)
        RD(a, b, rb + 32768);
        VMW(0);
        GBAR();
        stage(wb, 1, ke + 32);
        LGKM0();
        MFMA16X(a, b);
    }
    {   // ---- last K-tile: no staging ----
        const char* rb = smem + ((nsteps - 1) & 1) * 65536;
        RD(a, b, rb);
        VMW(0);                                // drain half1(last)
        GBAR();
        LGKM0();
        MFMA16X(a, b);
        RD(a, b, rb + 32768);
        LGKM0();
        MFMA16X(a, b);
    }
#undef RD
#undef MFMA16X

    asm volatile("s_nop 7\n\ts_nop 7");        // MFMA->VALU read hazard insurance

    const int crow = (lane >> 4) * 4;          // C/D: row = (lane>>4)*4 + reg
    const int ccol = lane & 15;                //      col = lane & 15

    #pragma unroll
    for (int m = 0; m < 4; ++m){
        #pragma unroll
        for (int n = 0; n < 4; ++n){
            const int gr = m0 + wr * 64 + m * 16 + crow;
            const int gc = n0 + wc * 64 + n * 16 + ccol;
            if (EPI == 1){
                #pragma unroll
                for (int r = 0; r < 4; ++r){
                    float sv = acc[m][n][r];
                    Wout[(size_t)(gr + r) * ldw + gc] = f2bf(__expf(10.0f * sv - 10.0f));
                }
            } else {
                #pragma unroll
                for (int r = 0; r < 4; ++r){
                    Fout[(size_t)(gr + r) * ldo + gc] =
                        Cadd[(size_t)(gr + r) * ldo + gc] + acc[m][n][r];
                }
            }
        }
    }
}

// ---------------------------------------------------------------------------
extern "C" void kernel_launch(void* const* d_in, const int* in_sizes, int n_in,
                              void* d_out, int out_size, void* d_ws, size_t ws_size,
                              hipStream_t stream)
{
    (void)n_in; (void)out_size;
    const float* inp = (const float*)d_in[0];
    const float* pos = (const float*)d_in[1];
    const float* off = (const float*)d_in[2];
    float* out = (float*)d_out;

    const int D = 1024, C = 2048;
    const int N = in_sizes[0] / D;            // 32768

    // workspace layout: b_bf[C*D] | offt[D*C] | a_bf[Mc*D] | w_buf[Mc*C]  (all bf16)
    unsigned short* b_bf = (unsigned short*)d_ws;
    unsigned short* offt = b_bf + (size_t)C * D;
    unsigned short* a_bf = offt + (size_t)D * C;
    size_t fixed = (size_t)C * D * 2 * 2;
    size_t avail = ws_size > fixed ? ws_size - fixed : 0;
    int Mc = 256;
    for (int cand = N; cand >= 256; cand >>= 1){
        if ((size_t)cand * (size_t)(D + C) * 2 <= avail){ Mc = cand; break; }
    }
    if (Mc > N) Mc = N;
    unsigned short* w_buf = a_bf + (size_t)Mc * D;

    hipFuncSetAttribute(reinterpret_cast<const void*>(&gemm256<1>),
                        hipFuncAttributeMaxDynamicSharedMemorySize, 131072);
    hipFuncSetAttribute(reinterpret_cast<const void*>(&gemm256<2>),
                        hipFuncAttributeMaxDynamicSharedMemorySize, 131072);

    float* reg_out = out + (size_t)N * D;
    hipMemsetAsync(reg_out, 0, sizeof(float), stream);

    transpose_off<<<dim3(C / 64, D / 64), 256, 0, stream>>>(off, offt, reg_out);
    norm_rows_bf16<<<C, 256, 0, stream>>>(pos, b_bf);

    for (int r0 = 0; r0 < N; r0 += Mc){
        norm_rows_bf16<<<Mc, 256, 0, stream>>>(inp + (size_t)r0 * D, a_bf);
        // GEMM1: W[Mc][C] = exp(10 * (a . b^T) - 10)
        gemm256<1><<<dim3(Mc / 256, C / 256), 1024, 131072, stream>>>(
            a_bf, D, b_bf, D, D, w_buf, C, nullptr, nullptr, 0);
        // GEMM2: out[Mc][D] = inp + W . offt^T
        gemm256<2><<<dim3(Mc / 256, D / 256), 1024, 131072, stream>>>(
            w_buf, C, offt, C, C, nullptr, 0, inp + (size_t)r0 * D, out + (size_t)r0 * D, D);
    }
    norm_rows_f32<<<N, 256, 0, stream>>>(out);
}

// Round 8
// 297.849 us; speedup vs baseline: 1.4122x; 1.4122x over previous
//
#include <hip/hip_runtime.h>

typedef float  f32x4  __attribute__((ext_vector_type(4)));
typedef float  f32x16 __attribute__((ext_vector_type(16)));
typedef int    i32x4  __attribute__((ext_vector_type(4)));
typedef int    i32x8  __attribute__((ext_vector_type(8)));

#define AS1 __attribute__((address_space(1)))
#define AS3 __attribute__((address_space(3)))

// ---- software float -> OCP e4m3fn (RNE), valid for |x| <= 448 ----
__device__ __forceinline__ unsigned int f2e4m3(float x){
    union{float f; unsigned u;} v; v.f = x;
    unsigned s = (v.u >> 24) & 0x80u;
    float ax = fabsf(x);
    if (ax > 448.0f) ax = 448.0f;
    if (ax < 0.015625f){                       // denormal: step 2^-9 (d=8 -> 2^-6, encoding works out)
        int d = (int)__builtin_rintf(ax * 512.0f);
        return s | (unsigned)d;
    }
    v.f = ax;
    unsigned u = v.u + 0x7ffffu + ((v.u >> 20) & 1u);   // RNE at 3-bit mantissa
    unsigned E = (u >> 23) - 120u;             // rebias 127 -> 7
    unsigned M = (u >> 20) & 7u;
    return s | (E << 3) | M;
}

__device__ __forceinline__ unsigned int pk4_e4m3(float x0, float x1, float x2, float x3){
    return f2e4m3(x0) | (f2e4m3(x1) << 8) | (f2e4m3(x2) << 16) | (f2e4m3(x3) << 24);
}

__device__ __forceinline__ void gload16(const unsigned char* g, const char* l){
    __builtin_amdgcn_global_load_lds((const AS1 void*)g, (AS3 void*)l, 16, 0, 0);
}

__device__ __forceinline__ i32x8 ld_frag(const char* p0, const char* p1){
    i32x4 lo = *(const i32x4*)p0;
    i32x4 hi = *(const i32x4*)p1;
    return __builtin_shufflevector(lo, hi, 0,1,2,3,4,5,6,7);
}

#define GBAR() do{ asm volatile("" ::: "memory"); __builtin_amdgcn_s_barrier(); \
                   asm volatile("" ::: "memory"); }while(0)
#define VMW(N)  asm volatile("s_waitcnt vmcnt(" #N ")" ::: "memory")
#define LGKM0() asm volatile("s_waitcnt lgkmcnt(0)" ::: "memory")

// ---------------------------------------------------------------------------
// Row l2-normalize [rows][1024] f32 -> fp8 e4m3 scaled by 16 (MX scale 2^-4).
// ---------------------------------------------------------------------------
__global__ __launch_bounds__(256) void norm_rows_fp8(const float* __restrict__ in,
                                                     unsigned int* __restrict__ out){
    const int row = blockIdx.x;
    const int t   = threadIdx.x;
    f32x4 x = ((const f32x4*)(in + (size_t)row * 1024))[t];
    float ss = x[0]*x[0] + x[1]*x[1] + x[2]*x[2] + x[3]*x[3];
    #pragma unroll
    for (int o = 32; o > 0; o >>= 1) ss += __shfl_xor(ss, o);
    __shared__ float red[4];
    if ((t & 63) == 0) red[t >> 6] = ss;
    __syncthreads();
    float tot = red[0] + red[1] + red[2] + red[3];
    float inv = 16.0f / fmaxf(sqrtf(tot), 1e-12f);
    out[(size_t)row * 256 + t] = pk4_e4m3(x[0]*inv, x[1]*inv, x[2]*inv, x[3]*inv);
}

// ---------------------------------------------------------------------------
// Final in-place row l2-normalize of d_out [N][1024] f32.
// ---------------------------------------------------------------------------
__global__ __launch_bounds__(256) void norm_rows_f32(float* __restrict__ buf){
    const int row = blockIdx.x;
    const int t   = threadIdx.x;
    f32x4* p = (f32x4*)(buf + (size_t)row * 1024);
    f32x4 x = p[t];
    float ss = x[0]*x[0] + x[1]*x[1] + x[2]*x[2] + x[3]*x[3];
    #pragma unroll
    for (int o = 32; o > 0; o >>= 1) ss += __shfl_xor(ss, o);
    __shared__ float red[4];
    if ((t & 63) == 0) red[t >> 6] = ss;
    __syncthreads();
    float tot = red[0] + red[1] + red[2] + red[3];
    float inv = 1.0f / fmaxf(sqrtf(tot), 1e-12f);
    p[t] = x * inv;
}

// ---------------------------------------------------------------------------
// offset [C=2048][D=1024] f32 -> offt [D][C] fp8 e4m3 scaled by 64 (2^-6),
// fused sum(offset^2) -> atomicAdd(reg_out). Tile: 64(c) x 64(d).
// ---------------------------------------------------------------------------
__global__ __launch_bounds__(256) void transpose_off(const float* __restrict__ off,
                                                     unsigned char* __restrict__ offt,
                                                     float* __restrict__ reg_out){
    __shared__ unsigned char t_lds[64][68];    // [d][c] bytes, padded row (68 % 4 == 0)
    const int t  = threadIdx.x;
    const int c0 = blockIdx.x * 64;
    const int d0 = blockIdx.y * 64;
    float ss = 0.f;
    #pragma unroll
    for (int p = 0; p < 4; ++p){
        int c  = p * 16 + (t >> 4);
        int dq = t & 15;
        f32x4 v = *(const f32x4*)(off + (size_t)(c0 + c) * 1024 + d0 + dq * 4);
        ss += v[0]*v[0] + v[1]*v[1] + v[2]*v[2] + v[3]*v[3];
        #pragma unroll
        for (int j = 0; j < 4; ++j) t_lds[dq * 4 + j][c] = (unsigned char)f2e4m3(v[j] * 64.0f);
    }
    __syncthreads();
    #pragma unroll
    for (int p = 0; p < 4; ++p){
        int d  = p * 16 + (t >> 4);
        int cq = t & 15;
        unsigned int o = *(const unsigned int*)&t_lds[d][cq * 4];
        *(unsigned int*)(offt + (size_t)(d0 + d) * 2048 + c0 + cq * 4) = o;
    }
    #pragma unroll
    for (int o = 32; o > 0; o >>= 1) ss += __shfl_xor(ss, o);
    __shared__ float red[4];
    if ((t & 63) == 0) red[t >> 6] = ss;
    __syncthreads();
    if (t == 0) atomicAdd(reg_out, red[0] + red[1] + red[2] + red[3]);
}

// ---------------------------------------------------------------------------
// FP8 GEMM: acc[m][n] = (2^(SA-127)*2^(SB-127)) * sum_k A[m][k]*B[n][k]
// (A,B fp8 e4m3, K-contiguous rows; lda/ldb in BYTES.)
// 256x256 tile, BK=128, 512 threads (8 waves, 2Mx4N; wave tile 128x64).
// mfma_scale_f32_32x32x64_f8f6f4 with UNIFORM scales (layout-permutation-
// immune via symmetric A/B load pattern; C/D = m101-verified 32x32 map).
// Double-buffered 128 KiB LDS; buffer = [Ak0|Bk0|Ak1|Bk1] 16KB quarters of
// [256 rows][64B], granule swizzle g ^= (row>>1)&3 (8-lane b128 groups cover
// all 32 banks) via pre-swizzled global source + swizzled ds_read.
// 4 phases/K-tile, r6-proven skeleton & vmcnt ledger:
//   P(p): reads -> [VMW(2) at P1,P3] -> barrier -> stage quarter(t+1)
//         -> lgkmcnt(0) -> setprio(1) + 4 MFMA + setprio(0)
// EPI==1: Wout[m][n] = e4m3(exp(10*acc-10) * 1024)   (ld = ldw bytes)
// EPI==2: Fout[m][n] = Cadd[m][n] + acc              (ld = ldo floats)
// ---------------------------------------------------------------------------
template<int EPI, int SA, int SB>
__global__ __launch_bounds__(512, 2)
void gemm256(const unsigned char* __restrict__ A, int lda,
             const unsigned char* __restrict__ B, int ldb,
             int K,
             unsigned char* __restrict__ Wout, int ldw,
             const float* __restrict__ Cadd, float* __restrict__ Fout, int ldo)
{
    extern __shared__ char smem[];             // 2 x 64 KiB
    const int tid  = threadIdx.x;

    // ---- XCD-aware bijective remap (8 XCDs; L2 locality on A panels) ----
    int bx = blockIdx.x, by = blockIdx.y;
    {
        const int gx = gridDim.x, gy = gridDim.y;
        const int nwg = gx * gy;
        if ((nwg & 7) == 0){
            const int lid = bx + gx * by;
            const int q   = nwg >> 3;
            const int n   = (lid & 7) * q + (lid >> 3);
            const int sh  = 31 - __clz(gy);    // gy is a power of two here
            bx = n >> sh;
            by = n & (gy - 1);
        }
    }
    const int m0   = bx * 256;
    const int n0   = by * 256;
    const int wid  = tid >> 6, lane = tid & 63;
    const int wr   = wid >> 2, wc = wid & 3;   // 2 x 4 waves, wave tile 128x64
    const int l31  = lane & 31, hg = lane >> 5;

    // ---- staging: quarter = [256 rows][4 granules of 16B]; thread t covers
    // (row=t>>2, g=t&3) and (row=128+(t>>2), g=t&3). logical granule =
    // (t&3) ^ ((row>>1)&3) -> pre-swizzled global source (same for both rows
    // since 128 rows -> +64 in (row>>1), = 0 mod 4).
    const int srow = tid >> 2;
    const int sg   = (tid & 3) ^ ((tid >> 3) & 3);
    const unsigned char* sA0 = A + (size_t)(m0 + srow)       * lda + sg * 16;
    const unsigned char* sA1 = A + (size_t)(m0 + 128 + srow) * lda + sg * 16;
    const unsigned char* sB0 = B + (size_t)(n0 + srow)       * ldb + sg * 16;
    const unsigned char* sB1 = B + (size_t)(n0 + 128 + srow) * ldb + sg * 16;
    const int lp0 = tid * 16, lp1 = 8192 + tid * 16;

    auto stageA = [&](char* wb, int qbase, int koff){
        gload16(sA0 + koff, wb + qbase + lp0);
        gload16(sA1 + koff, wb + qbase + lp1);
    };
    auto stageB = [&](char* wb, int qbase, int koff){
        gload16(sB0 + koff, wb + qbase + lp0);
        gload16(sB1 + koff, wb + qbase + lp1);
    };

    // ---- ds_read fragment offsets within a quarter (swizzled) ----
    // frag (m): lane holds row = base + l31 (32 rows), 32 contiguous k-bytes
    // = 2 b128 at granules ((hg*2+j) ^ ((row>>1)&3)).
    int aoff[4][2], boff[2][2];
    #pragma unroll
    for (int m = 0; m < 4; ++m){
        int row = wr * 128 + m * 32 + l31;
        int sw  = (row >> 1) & 3;
        aoff[m][0] = row * 64 + (((hg << 1) | 0) ^ sw) * 16;
        aoff[m][1] = row * 64 + (((hg << 1) | 1) ^ sw) * 16;
    }
    #pragma unroll
    for (int n = 0; n < 2; ++n){
        int row = wc * 64 + n * 32 + l31;
        int sw  = (row >> 1) & 3;
        boff[n][0] = 16384 + row * 64 + (((hg << 1) | 0) ^ sw) * 16;
        boff[n][1] = 16384 + row * 64 + (((hg << 1) | 1) ^ sw) * 16;
    }

    f32x16 acc[4][2] = {};
    const int nsteps = K >> 7;                 // BK = 128

    // ---- prologue: stage tile 0 (Q0..Q3 = 8 loads); wait Q0,Q1 ----
    {
        char* wb = smem;
        stageA(wb, 0,     0);  stageB(wb, 16384, 0);
        stageA(wb, 32768, 64); stageB(wb, 49152, 64);
    }
    VMW(4);
    GBAR();

#define RD_A2(dst, rbq, mb) { \
    dst[0] = ld_frag((rbq) + aoff[(mb)][0],   (rbq) + aoff[(mb)][1]); \
    dst[1] = ld_frag((rbq) + aoff[(mb)+1][0], (rbq) + aoff[(mb)+1][1]); }
#define RD_B2(dst, rbq) { \
    dst[0] = ld_frag((rbq) + boff[0][0], (rbq) + boff[0][1]); \
    dst[1] = ld_frag((rbq) + boff[1][0], (rbq) + boff[1][1]); }
#define MFMA4(mb, av, bv) { __builtin_amdgcn_s_setprio(1); \
    _Pragma("unroll") for (int mi = 0; mi < 2; ++mi) \
    _Pragma("unroll") for (int ni = 0; ni < 2; ++ni) \
        acc[(mb)+mi][ni] = __builtin_amdgcn_mfma_scale_f32_32x32x64_f8f6f4( \
            av[mi], bv[ni], acc[(mb)+mi][ni], 0, 0, 0, SA, 0, SB); \
    __builtin_amdgcn_s_setprio(0); }

    i32x8 fa[2], fb[2];

    #pragma unroll 1
    for (int t = 0; t < nsteps - 1; ++t){
        const char* rb = smem + (t & 1) * 65536;
        char*       wb = smem + ((t + 1) & 1) * 65536;
        const int   ke = (t + 1) * 128;        // k-byte offset of tile t+1
        // P0: reads m0-1,B of ki0; stage Q0(t+1)
        RD_A2(fa, rb, 0); RD_B2(fb, rb);
        GBAR();
        stageA(wb, 0, ke);
        LGKM0();
        MFMA4(0, fa, fb);
        // P1: reads m2-3 ki0; VMW drains Q2,Q3(t); stage Q1(t+1)
        RD_A2(fa, rb, 2);
        VMW(2);
        GBAR();
        stageB(wb, 16384, ke);
        LGKM0();
        MFMA4(2, fa, fb);
        // P2: reads m0-1,B of ki1; stage Q2(t+1)
        RD_A2(fa, rb + 32768, 0); RD_B2(fb, rb + 32768);
        GBAR();
        stageA(wb, 32768, ke + 64);
        LGKM0();
        MFMA4(0, fa, fb);
        // P3: reads m2-3 ki1; VMW drains Q0,Q1(t+1); stage Q3(t+1)
        RD_A2(fa, rb + 32768, 2);
        VMW(2);
        GBAR();
        stageB(wb, 49152, ke + 64);
        LGKM0();
        MFMA4(2, fa, fb);
    }
    {   // ---- last K-tile: no staging; drain Q2,Q3(last) before ki1 reads ----
        const char* rb = smem + ((nsteps - 1) & 1) * 65536;
        RD_A2(fa, rb, 0); RD_B2(fb, rb);
        GBAR();
        LGKM0();
        MFMA4(0, fa, fb);
        RD_A2(fa, rb, 2);
        VMW(0);
        GBAR();
        LGKM0();
        MFMA4(2, fa, fb);
        RD_A2(fa, rb + 32768, 0); RD_B2(fb, rb + 32768);
        GBAR();
        LGKM0();
        MFMA4(0, fa, fb);
        RD_A2(fa, rb + 32768, 2);
        GBAR();
        LGKM0();
        MFMA4(2, fa, fb);
    }
#undef RD_A2
#undef RD_B2
#undef MFMA4

    asm volatile("s_nop 7\n\ts_nop 7");        // MFMA->VALU read hazard insurance

    // C/D layout (32x32): col = lane&31, row = (r&3) + 8*(r>>2) + 4*(lane>>5)
    #pragma unroll
    for (int m = 0; m < 4; ++m){
        #pragma unroll
        for (int n = 0; n < 2; ++n){
            const int grb = m0 + wr * 128 + m * 32;
            const int gc  = n0 + wc * 64  + n * 32 + l31;
            #pragma unroll
            for (int r = 0; r < 16; ++r){
                const int row = (r & 3) + 8 * (r >> 2) + 4 * hg;
                if (EPI == 1){
                    float w = __expf(10.0f * acc[m][n][r] - 10.0f) * 1024.0f;
                    Wout[(size_t)(grb + row) * ldw + gc] = (unsigned char)f2e4m3(w);
                } else {
                    Fout[(size_t)(grb + row) * ldo + gc] =
                        Cadd[(size_t)(grb + row) * ldo + gc] + acc[m][n][r];
                }
            }
        }
    }
}

// ---------------------------------------------------------------------------
extern "C" void kernel_launch(void* const* d_in, const int* in_sizes, int n_in,
                              void* d_out, int out_size, void* d_ws, size_t ws_size,
                              hipStream_t stream)
{
    (void)n_in; (void)out_size;
    const float* inp = (const float*)d_in[0];
    const float* pos = (const float*)d_in[1];
    const float* off = (const float*)d_in[2];
    float* out = (float*)d_out;

    const int D = 1024, C = 2048;
    const int N = in_sizes[0] / D;            // 32768

    // workspace (bytes): b_fp8[C*D] | offt[D*C] | a_fp8[Mc*D] | w_buf[Mc*C]
    unsigned char* b_fp8 = (unsigned char*)d_ws;
    unsigned char* offt  = b_fp8 + (size_t)C * D;
    unsigned char* a_fp8 = offt + (size_t)D * C;
    size_t fixed = (size_t)C * D * 2;
    size_t avail = ws_size > fixed ? ws_size - fixed : 0;
    int Mc = 256;
    for (int cand = N; cand >= 256; cand >>= 1){
        if ((size_t)cand * (size_t)(D + C) <= avail){ Mc = cand; break; }
    }
    if (Mc > N) Mc = N;
    unsigned char* w_buf = a_fp8 + (size_t)Mc * D;

    // scales (e8m0 byte, value 2^(b-127)):
    // GEMM1: a,pos stored *16 -> SA=SB=123 (2^-4 each)
    // GEMM2: W stored *1024 -> SA=117 (2^-10); offt stored *64 -> SB=121 (2^-6)
    hipFuncSetAttribute(reinterpret_cast<const void*>(&gemm256<1,123,123>),
                        hipFuncAttributeMaxDynamicSharedMemorySize, 131072);
    hipFuncSetAttribute(reinterpret_cast<const void*>(&gemm256<2,117,121>),
                        hipFuncAttributeMaxDynamicSharedMemorySize, 131072);

    float* reg_out = out + (size_t)N * D;
    hipMemsetAsync(reg_out, 0, sizeof(float), stream);

    transpose_off<<<dim3(C / 64, D / 64), 256, 0, stream>>>(off, offt, reg_out);
    norm_rows_fp8<<<C, 256, 0, stream>>>(pos, (unsigned int*)b_fp8);

    for (int r0 = 0; r0 < N; r0 += Mc){
        norm_rows_fp8<<<Mc, 256, 0, stream>>>(inp + (size_t)r0 * D, (unsigned int*)a_fp8);
        // GEMM1: W[Mc][C] = e4m3(1024 * exp(10*(a.b^T) - 10))
        gemm256<1,123,123><<<dim3(Mc / 256, C / 256), 512, 131072, stream>>>(
            a_fp8, D, b_fp8, D, D, w_buf, C, nullptr, nullptr, 0);
        // GEMM2: out[Mc][D] = inp + (2^-16 scaled) W . offt^T
        gemm256<2,117,121><<<dim3(Mc / 256, D / 256), 512, 131072, stream>>>(
            w_buf, C, offt, C, C, nullptr, 0, inp + (size_t)r0 * D, out + (size_t)r0 * D, D);
    }
    norm_rows_f32<<<N, 256, 0, stream>>>(out);
}

// Round 9
// 278.903 us; speedup vs baseline: 1.5081x; 1.0679x over previous
//
#include <hip/hip_runtime.h>

typedef float  f32x4  __attribute__((ext_vector_type(4)));
typedef float  f32x16 __attribute__((ext_vector_type(16)));
typedef int    i32x4  __attribute__((ext_vector_type(4)));
typedef int    i32x8  __attribute__((ext_vector_type(8)));

#define AS1 __attribute__((address_space(1)))
#define AS3 __attribute__((address_space(3)))

// ---- software float -> OCP e4m3fn (RNE), valid for |x| <= 448 ----
__device__ __forceinline__ unsigned int f2e4m3(float x){
    union{float f; unsigned u;} v; v.f = x;
    unsigned s = (v.u >> 24) & 0x80u;
    float ax = fabsf(x);
    if (ax > 448.0f) ax = 448.0f;
    if (ax < 0.015625f){
        int d = (int)__builtin_rintf(ax * 512.0f);
        return s | (unsigned)d;
    }
    v.f = ax;
    unsigned u = v.u + 0x7ffffu + ((v.u >> 20) & 1u);
    unsigned E = (u >> 23) - 120u;
    unsigned M = (u >> 20) & 7u;
    return s | (E << 3) | M;
}

// ---- 4 floats -> packed 4x e4m3 (HW cvt if available) ----
__device__ __forceinline__ unsigned int pk4(float x0, float x1, float x2, float x3){
#if __has_builtin(__builtin_amdgcn_cvt_pk_fp8_f32)
    int u = __builtin_amdgcn_cvt_pk_fp8_f32(x0, x1, 0, false);
    u     = __builtin_amdgcn_cvt_pk_fp8_f32(x2, x3, u, true);
    return (unsigned)u;
#else
    return f2e4m3(x0) | (f2e4m3(x1) << 8) | (f2e4m3(x2) << 16) | (f2e4m3(x3) << 24);
#endif
}

__device__ __forceinline__ void gload16(const unsigned char* g, const char* l){
    __builtin_amdgcn_global_load_lds((const AS1 void*)g, (AS3 void*)l, 16, 0, 0);
}

__device__ __forceinline__ i32x8 ld_frag(const char* p0, const char* p1){
    i32x4 lo = *(const i32x4*)p0;
    i32x4 hi = *(const i32x4*)p1;
    return __builtin_shufflevector(lo, hi, 0,1,2,3,4,5,6,7);
}

#define GBAR() do{ asm volatile("" ::: "memory"); __builtin_amdgcn_s_barrier(); \
                   asm volatile("" ::: "memory"); }while(0)
#define VMW(N)  asm volatile("s_waitcnt vmcnt(" #N ")" ::: "memory")

// ---------------------------------------------------------------------------
// Row l2-normalize [rows][1024] f32 -> fp8 e4m3 scaled by 16 (MX scale 2^-4).
// ---------------------------------------------------------------------------
__global__ __launch_bounds__(256) void norm_rows_fp8(const float* __restrict__ in,
                                                     unsigned int* __restrict__ out){
    const int row = blockIdx.x;
    const int t   = threadIdx.x;
    f32x4 x = ((const f32x4*)(in + (size_t)row * 1024))[t];
    float ss = x[0]*x[0] + x[1]*x[1] + x[2]*x[2] + x[3]*x[3];
    #pragma unroll
    for (int o = 32; o > 0; o >>= 1) ss += __shfl_xor(ss, o);
    __shared__ float red[4];
    if ((t & 63) == 0) red[t >> 6] = ss;
    __syncthreads();
    float tot = red[0] + red[1] + red[2] + red[3];
    float inv = 16.0f / fmaxf(sqrtf(tot), 1e-12f);
    out[(size_t)row * 256 + t] = pk4(x[0]*inv, x[1]*inv, x[2]*inv, x[3]*inv);
}

// ---------------------------------------------------------------------------
// Final in-place row l2-normalize of d_out [N][1024] f32.
// ---------------------------------------------------------------------------
__global__ __launch_bounds__(256) void norm_rows_f32(float* __restrict__ buf){
    const int row = blockIdx.x;
    const int t   = threadIdx.x;
    f32x4* p = (f32x4*)(buf + (size_t)row * 1024);
    f32x4 x = p[t];
    float ss = x[0]*x[0] + x[1]*x[1] + x[2]*x[2] + x[3]*x[3];
    #pragma unroll
    for (int o = 32; o > 0; o >>= 1) ss += __shfl_xor(ss, o);
    __shared__ float red[4];
    if ((t & 63) == 0) red[t >> 6] = ss;
    __syncthreads();
    float tot = red[0] + red[1] + red[2] + red[3];
    float inv = 1.0f / fmaxf(sqrtf(tot), 1e-12f);
    p[t] = x * inv;
}

// ---------------------------------------------------------------------------
// offset [C=2048][D=1024] f32 -> offt [D][C] fp8 e4m3 scaled by 64 (2^-6),
// fused sum(offset^2) -> atomicAdd(reg_out). Tile: 64(c) x 64(d).
// ---------------------------------------------------------------------------
__global__ __launch_bounds__(256) void transpose_off(const float* __restrict__ off,
                                                     unsigned char* __restrict__ offt,
                                                     float* __restrict__ reg_out){
    __shared__ unsigned char t_lds[64][68];
    const int t  = threadIdx.x;
    const int c0 = blockIdx.x * 64;
    const int d0 = blockIdx.y * 64;
    float ss = 0.f;
    #pragma unroll
    for (int p = 0; p < 4; ++p){
        int c  = p * 16 + (t >> 4);
        int dq = t & 15;
        f32x4 v = *(const f32x4*)(off + (size_t)(c0 + c) * 1024 + d0 + dq * 4);
        ss += v[0]*v[0] + v[1]*v[1] + v[2]*v[2] + v[3]*v[3];
        unsigned u = pk4(v[0]*64.0f, v[1]*64.0f, v[2]*64.0f, v[3]*64.0f);
        #pragma unroll
        for (int j = 0; j < 4; ++j) t_lds[dq * 4 + j][c] = (unsigned char)(u >> (8*j));
    }
    __syncthreads();
    #pragma unroll
    for (int p = 0; p < 4; ++p){
        int d  = p * 16 + (t >> 4);
        int cq = t & 15;
        unsigned int o = *(const unsigned int*)&t_lds[d][cq * 4];
        *(unsigned int*)(offt + (size_t)(d0 + d) * 2048 + c0 + cq * 4) = o;
    }
    #pragma unroll
    for (int o = 32; o > 0; o >>= 1) ss += __shfl_xor(ss, o);
    __shared__ float red[4];
    if ((t & 63) == 0) red[t >> 6] = ss;
    __syncthreads();
    if (t == 0) atomicAdd(reg_out, red[0] + red[1] + red[2] + red[3]);
}

// ---------------------------------------------------------------------------
// FP8 GEMM: acc[m][n] = 2^(SA-127)*2^(SB-127) * sum_k A[m][k]*B[n][k]
// (A,B fp8 e4m3, K-contiguous rows; lda/ldb in BYTES.)
// 256x128 tile, BK=64, 256 threads (4 waves 2Mx2N; wave tile 128x64) ->
// 72 KiB LDS => TWO independent blocks/CU (cross-block stall overlap, m114).
// mfma_scale_f32_32x32x64_f8f6f4, uniform scales. Tri-buffered LDS
// (3 x [A 16KB | B 8KB]); stage->consume distance = 2 K-tiles (> HBM lat).
// One barrier + one counted VMW(6) per K-tile; no lgkmcnt drains (builtin
// MFMA => compiler-counted lgkm). Granule swizzle g ^= (row>>1)&3 via
// pre-swizzled global source + swizzled ds_read.
// Safety: stage(t+2) overwrites buf read at t-1; every wave's t-1 reads
// completed before its t-1 MFMAs, which precede GBAR(t-1) -> safe.
// EPI==1: Wout = e4m3(exp(10*acc-10)*1024) via exp2+cvt_pk  (ldw bytes)
// EPI==2: Fout = Cadd + acc                                  (ldo floats)
// ---------------------------------------------------------------------------
template<int EPI, int SA, int SB>
__global__ __launch_bounds__(256, 2)
void gemm256(const unsigned char* __restrict__ A, int lda,
             const unsigned char* __restrict__ B, int ldb,
             int K,
             unsigned char* __restrict__ Wout, int ldw,
             const float* __restrict__ Cadd, float* __restrict__ Fout, int ldo)
{
    extern __shared__ char smem[];             // 3 x 24 KiB
    const int tid  = threadIdx.x;

    // ---- XCD-aware bijective remap ----
    int bx = blockIdx.x, by = blockIdx.y;
    {
        const int gx = gridDim.x, gy = gridDim.y;
        const int nwg = gx * gy;
        if ((nwg & 7) == 0){
            const int lid = bx + gx * by;
            const int q   = nwg >> 3;
            const int n   = (lid & 7) * q + (lid >> 3);
            const int sh  = 31 - __clz(gy);    // gy is a power of two
            bx = n >> sh;
            by = n & (gy - 1);
        }
    }
    const int m0   = bx * 256;
    const int n0   = by * 128;
    const int wid  = tid >> 6, lane = tid & 63;
    const int wr   = wid >> 1, wc = wid & 1;   // 2x2 waves, wave tile 128x64
    const int l31  = lane & 31, hg = lane >> 5;

    // ---- staging: A 16KB (256 rows x 64B), B 8KB (128 rows x 64B) ----
    // thread t -> rows (t>>2)+64j, phys granule t&3 holds logical
    // (t&3)^((row>>1)&3); +64 rows preserves the XOR -> one sg for all j.
    const int srow = tid >> 2;
    const int sg   = (tid & 3) ^ ((tid >> 3) & 3);
    const unsigned char* sA = A + (size_t)(m0 + srow) * lda + sg * 16;
    const unsigned char* sB = B + (size_t)(n0 + srow) * ldb + sg * 16;
    const int lp = tid * 16;

    auto stgA = [&](char* wb, int ke){
        #pragma unroll
        for (int j = 0; j < 4; ++j)
            gload16(sA + (size_t)j * 64 * lda + ke, wb + j * 4096 + lp);
    };
    auto stgB = [&](char* wb, int ke){
        #pragma unroll
        for (int j = 0; j < 2; ++j)
            gload16(sB + (size_t)j * 64 * ldb + ke, wb + 16384 + j * 4096 + lp);
    };

    // ---- frag read offsets (swizzled): lane row = base + l31, 32 k-bytes
    // = 2 b128 at granules (2hg+j) ^ ((row>>1)&3) ----
    int aoff[4][2], boff[2][2];
    #pragma unroll
    for (int m = 0; m < 4; ++m){
        int row = wr * 128 + m * 32 + l31;
        int sw  = (row >> 1) & 3;
        aoff[m][0] = row * 64 + (((hg << 1) | 0) ^ sw) * 16;
        aoff[m][1] = row * 64 + (((hg << 1) | 1) ^ sw) * 16;
    }
    #pragma unroll
    for (int n = 0; n < 2; ++n){
        int row = wc * 64 + n * 32 + l31;
        int sw  = (row >> 1) & 3;
        boff[n][0] = 16384 + row * 64 + (((hg << 1) | 0) ^ sw) * 16;
        boff[n][1] = 16384 + row * 64 + (((hg << 1) | 1) ^ sw) * 16;
    }

    f32x16 acc[4][2] = {};
    const int nsteps = K >> 6;                 // BK = 64

#define RD_A(mb) { \
    fa[0] = ld_frag(b0 + aoff[(mb)][0],   b0 + aoff[(mb)][1]); \
    fa[1] = ld_frag(b0 + aoff[(mb)+1][0], b0 + aoff[(mb)+1][1]); }
#define RD_B()   { \
    fb[0] = ld_frag(b0 + boff[0][0], b0 + boff[0][1]); \
    fb[1] = ld_frag(b0 + boff[1][0], b0 + boff[1][1]); }
#define MFMA4(mb) { __builtin_amdgcn_s_setprio(1); \
    _Pragma("unroll") for (int mi = 0; mi < 2; ++mi) \
    _Pragma("unroll") for (int ni = 0; ni < 2; ++ni) \
        acc[(mb)+mi][ni] = __builtin_amdgcn_mfma_scale_f32_32x32x64_f8f6f4( \
            fa[mi], fb[ni], acc[(mb)+mi][ni], 0, 0, 0, SA, 0, SB); \
    __builtin_amdgcn_s_setprio(0); }

    i32x8 fa[2], fb[2];
    char* b0 = smem;
    char* b1 = smem + 24576;
    char* b2 = smem + 49152;

    // ---- prologue: stage tiles 0,1 (12 loads); wait tile 0 (6) ----
    stgA(b0, 0);  stgB(b0, 0);
    stgA(b1, 64); stgB(b1, 64);
    VMW(6);
    GBAR();

    int ke = 128;                              // k-byte offset of tile t+2
    #pragma unroll 1
    for (int t = 0; t < nsteps - 2; ++t){
        RD_A(0); RD_B();
        stgA(b2, ke);
        MFMA4(0);
        RD_A(2);
        stgB(b2, ke);
        MFMA4(2);
        VMW(6);                                // drain tile t+1; keep t+2 in flight
        GBAR();
        char* tmp = b0; b0 = b1; b1 = b2; b2 = tmp;
        ke += 64;
    }
    // t = nsteps-2 (no staging; drain last tile's loads at end)
    RD_A(0); RD_B();
    MFMA4(0);
    RD_A(2);
    MFMA4(2);
    VMW(0);
    GBAR();
    // t = nsteps-1
    { char* tmp = b0; b0 = b1; b1 = tmp; }
    RD_A(0); RD_B();
    MFMA4(0);
    RD_A(2);
    MFMA4(2);

#undef RD_A
#undef RD_B
#undef MFMA4

    asm volatile("s_nop 7\n\ts_nop 7");

    // C/D layout (32x32): col = lane&31, row = (r&3) + 8*(r>>2) + 4*(lane>>5)
    #pragma unroll
    for (int m = 0; m < 4; ++m){
        #pragma unroll
        for (int n = 0; n < 2; ++n){
            const int grb = m0 + wr * 128 + m * 32;
            const int gc  = n0 + wc * 64  + n * 32 + l31;
            if (EPI == 1){
                #pragma unroll
                for (int q = 0; q < 4; ++q){
                    const int row0 = grb + 8 * q + 4 * hg;   // rows row0..row0+3
                    float w0 = exp2f(fmaf(14.4269504f, acc[m][n][4*q+0], -4.4269504f));
                    float w1 = exp2f(fmaf(14.4269504f, acc[m][n][4*q+1], -4.4269504f));
                    float w2 = exp2f(fmaf(14.4269504f, acc[m][n][4*q+2], -4.4269504f));
                    float w3 = exp2f(fmaf(14.4269504f, acc[m][n][4*q+3], -4.4269504f));
                    unsigned u = pk4(w0, w1, w2, w3);
                    unsigned char* p = Wout + (size_t)row0 * ldw + gc;
                    p[0]                = (unsigned char)u;
                    p[(size_t)ldw]      = (unsigned char)(u >> 8);
                    p[(size_t)ldw * 2]  = (unsigned char)(u >> 16);
                    p[(size_t)ldw * 3]  = (unsigned char)(u >> 24);
                }
            } else {
                #pragma unroll
                for (int r = 0; r < 16; ++r){
                    const int row = (r & 3) + 8 * (r >> 2) + 4 * hg;
                    Fout[(size_t)(grb + row) * ldo + gc] =
                        Cadd[(size_t)(grb + row) * ldo + gc] + acc[m][n][r];
                }
            }
        }
    }
}

// ---------------------------------------------------------------------------
extern "C" void kernel_launch(void* const* d_in, const int* in_sizes, int n_in,
                              void* d_out, int out_size, void* d_ws, size_t ws_size,
                              hipStream_t stream)
{
    (void)n_in; (void)out_size;
    const float* inp = (const float*)d_in[0];
    const float* pos = (const float*)d_in[1];
    const float* off = (const float*)d_in[2];
    float* out = (float*)d_out;

    const int D = 1024, C = 2048;
    const int N = in_sizes[0] / D;            // 32768

    // workspace (bytes): b_fp8[C*D] | offt[D*C] | a_fp8[Mc*D] | w_buf[Mc*C]
    unsigned char* b_fp8 = (unsigned char*)d_ws;
    unsigned char* offt  = b_fp8 + (size_t)C * D;
    unsigned char* a_fp8 = offt + (size_t)D * C;
    size_t fixed = (size_t)C * D * 2;
    size_t avail = ws_size > fixed ? ws_size - fixed : 0;
    int Mc = 256;
    for (int cand = N; cand >= 256; cand >>= 1){
        if ((size_t)cand * (size_t)(D + C) <= avail){ Mc = cand; break; }
    }
    if (Mc > N) Mc = N;
    unsigned char* w_buf = a_fp8 + (size_t)Mc * D;

    // scales (e8m0, 2^(b-127)): GEMM1 a,pos *16 -> 123,123;
    // GEMM2 W *1024 -> 117, offt *64 -> 121.
    hipFuncSetAttribute(reinterpret_cast<const void*>(&gemm256<1,123,123>),
                        hipFuncAttributeMaxDynamicSharedMemorySize, 73728);
    hipFuncSetAttribute(reinterpret_cast<const void*>(&gemm256<2,117,121>),
                        hipFuncAttributeMaxDynamicSharedMemorySize, 73728);

    float* reg_out = out + (size_t)N * D;
    hipMemsetAsync(reg_out, 0, sizeof(float), stream);

    transpose_off<<<dim3(C / 64, D / 64), 256, 0, stream>>>(off, offt, reg_out);
    norm_rows_fp8<<<C, 256, 0, stream>>>(pos, (unsigned int*)b_fp8);

    for (int r0 = 0; r0 < N; r0 += Mc){
        norm_rows_fp8<<<Mc, 256, 0, stream>>>(inp + (size_t)r0 * D, (unsigned int*)a_fp8);
        // GEMM1: W[Mc][C] = e4m3(1024 * exp(10*(a.b^T) - 10))
        gemm256<1,123,123><<<dim3(Mc / 256, C / 128), 256, 73728, stream>>>(
            a_fp8, D, b_fp8, D, D, w_buf, C, nullptr, nullptr, 0);
        // GEMM2: out[Mc][D] = inp + (2^-16 scaled) W . offt^T
        gemm256<2,117,121><<<dim3(Mc / 256, D / 128), 256, 73728, stream>>>(
            w_buf, C, offt, C, C, nullptr, 0, inp + (size_t)r0 * D, out + (size_t)r0 * D, D);
    }
    norm_rows_f32<<<N, 256, 0, stream>>>(out);
}